// Round 9
// baseline (1092.944 us; speedup 1.0000x reference)
//
#include <hip/hip_runtime.h>
#include <hip/hip_fp16.h>

#define NSITES 500000
#define KOFF   27
#define RPAIR  250000
#define KR     (KOFF * RPAIR)            // 6,750,000 pairs
#define CIN    16
#define COUT   16
#define NBUCK  1954                      // output bucket = o >> 8
#define NSLC   8                         // input slice  = in >> 16 (0..7)
#define NSEG   (NBUCK * NSLC)            // 15632 segments (b-major, slice-minor)
#define NBLK   256                       // preprocessing blocks
#define CHUNK  ((KR + NBLK - 1) / NBLK)  // 26368 pairs per block
#define ASTRIDE 17                       // LDS acc row stride
#define PROWS  (NBUCK * 256)             // 500224 rows per partial plane

// native clang vector type (allowed by __builtin_nontemporal_*)
typedef unsigned uvec4 __attribute__((ext_vector_type(4)));

// ---------------- workspace layout (BYTE offsets) ----------------
// countsT ushort[NBLK][NSEG]   8,003,584 B
// PT      ushort[NBLK][NSEG]   8,003,584 B
// Ttot    int[NSEG]               62,528 B
// cstart  int[NSEG+1]             62,532 B (+pad)
// entries uint[KR]            27,000,000 B
// fbf16   uint4[NSITES*2]     16,000,000 B
// partials half[NSLC][PROWS][16]  128,057,344 B
#define OFF_CNT   0ull
#define OFF_PT    8003584ull
#define OFF_TTOT  16007168ull
#define OFF_CST   16069696ull
#define OFF_ENT   16132288ull
#define OFF_FB    43132288ull
#define OFF_PART  59132288ull
#define NEED_FULL 187189632ull
#define NEED_MID  59132288ull

// ---------------------------------------------------------------------------
// Pass 0: features f32 -> packed bf16 rows (32 B/row), RNE
// ---------------------------------------------------------------------------
__global__ __launch_bounds__(256) void convert_bf16_kernel(
    const float* __restrict__ f, uint4* __restrict__ fb)
{
    const int r = blockIdx.x * 256 + threadIdx.x;
    if (r >= NSITES) return;
    const uint4* src = (const uint4*)(f + (size_t)r * CIN);
    const uint4 a = src[0], b = src[1], c = src[2], d = src[3];
#define BF(x) (((x) + 0x7FFFu + (((x) >> 16) & 1u)) >> 16)
    uint4 o0, o1;
    o0.x = BF(a.x) | (BF(a.y) << 16);
    o0.y = BF(a.z) | (BF(a.w) << 16);
    o0.z = BF(b.x) | (BF(b.y) << 16);
    o0.w = BF(b.z) | (BF(b.w) << 16);
    o1.x = BF(c.x) | (BF(c.y) << 16);
    o1.y = BF(c.z) | (BF(c.w) << 16);
    o1.z = BF(d.x) | (BF(d.y) << 16);
    o1.w = BF(d.z) | (BF(d.w) << 16);
#undef BF
    fb[(size_t)r * 2]     = o0;
    fb[(size_t)r * 2 + 1] = o1;
}

// ---------------------------------------------------------------------------
// passA: per-(block, segment) counts via LDS. seg = (o>>8)*8 + (in>>16).
// ---------------------------------------------------------------------------
__global__ __launch_bounds__(256) void passA_kernel(
    const int* __restrict__ rules_in, const int* __restrict__ rules_out,
    unsigned short* __restrict__ countsT)
{
    __shared__ unsigned cnt[NSEG];
    for (int i = threadIdx.x; i < NSEG; i += 256) cnt[i] = 0;
    __syncthreads();
    const int base = blockIdx.x * CHUNK;
    const int end  = (base + CHUNK < KR) ? base + CHUNK : KR;
    for (int p = base + threadIdx.x; p < end; p += 256) {
        const int o  = __builtin_nontemporal_load(rules_out + p);
        const int in = __builtin_nontemporal_load(rules_in + p);
        atomicAdd(&cnt[((o >> 8) << 3) | (in >> 16)], 1u);
    }
    __syncthreads();
    unsigned short* row = countsT + (size_t)blockIdx.x * NSEG;
    for (int i = threadIdx.x; i < NSEG; i += 256)
        row[i] = (unsigned short)cnt[i];
}

// ---------------------------------------------------------------------------
// scanK1: per-segment prefix over blocks -> PT[blk][seg]; totals -> Ttot
// ---------------------------------------------------------------------------
__global__ __launch_bounds__(256) void scanK1_kernel(
    const unsigned short* __restrict__ countsT,
    unsigned short* __restrict__ PT, int* __restrict__ Ttot)
{
    const int c = blockIdx.x * 256 + threadIdx.x;
    if (c >= NSEG) return;
    unsigned run = 0;
    for (int g = 0; g < NBLK; ++g) {
        PT[(size_t)g * NSEG + c] = (unsigned short)run;
        run += countsT[(size_t)g * NSEG + c];
    }
    Ttot[c] = (int)run;
}

// ---------------------------------------------------------------------------
// scanK2: exclusive scan of Ttot[NSEG] -> cstart (+ sentinel)
// ---------------------------------------------------------------------------
__global__ __launch_bounds__(1024) void scanK2_kernel(
    const int* __restrict__ Ttot, int* __restrict__ cstart)
{
    __shared__ int s[1024];
    __shared__ int base_s;
    const int t = threadIdx.x;
    if (t == 0) base_s = 0;
    __syncthreads();
    for (int chunk = 0; chunk < (NSEG + 1023) / 1024; ++chunk) {
        const int i = chunk * 1024 + t;
        const int v = (i < NSEG) ? Ttot[i] : 0;
        s[t] = v;
        __syncthreads();
        for (int off = 1; off < 1024; off <<= 1) {
            int u = (t >= off) ? s[t - off] : 0;
            __syncthreads();
            s[t] += u;
            __syncthreads();
        }
        if (i < NSEG) cstart[i] = base_s + s[t] - v;
        __syncthreads();
        if (t == 1023) base_s += s[1023];
        __syncthreads();
    }
    if (t == 0) cstart[NSEG] = KR;
}

// ---------------------------------------------------------------------------
// passB: deterministic placement into (b, slice)-segmented entries.
// ---------------------------------------------------------------------------
__global__ __launch_bounds__(256) void passB_kernel(
    const int* __restrict__ rules_in, const int* __restrict__ rules_out,
    const int* __restrict__ cstart, const unsigned short* __restrict__ PT,
    unsigned* __restrict__ entries)
{
    __shared__ unsigned cur[NSEG];
    for (int i = threadIdx.x; i < NSEG; i += 256) cur[i] = 0;
    __syncthreads();
    const int base = blockIdx.x * CHUNK;
    const int end  = (base + CHUNK < KR) ? base + CHUNK : KR;
    const unsigned short* pt = PT + (size_t)blockIdx.x * NSEG;
    for (int p = base + threadIdx.x; p < end; p += 256) {
        const int o   = __builtin_nontemporal_load(rules_out + p);
        const int in  = __builtin_nontemporal_load(rules_in + p);
        const int seg = ((o >> 8) << 3) | (in >> 16);
        const int k   = p / RPAIR;
        const unsigned rank = atomicAdd(&cur[seg], 1u);
        const int pos = cstart[seg] + (int)pt[seg] + (int)rank;
        entries[pos] = (unsigned)in | ((unsigned)k << 19) |
                       ((unsigned)(o & 255) << 24);
    }
}

// ---------------------------------------------------------------------------
// shared per-entry math
// ---------------------------------------------------------------------------
__device__ __forceinline__ void fma4(float4& a, float s, const float4 w) {
    a.x = fmaf(s, w.x, a.x);
    a.y = fmaf(s, w.y, a.y);
    a.z = fmaf(s, w.z, a.z);
    a.w = fmaf(s, w.w, a.w);
}

template <int BF16>
__device__ __forceinline__ void process_entry(
    unsigned v, const uint4* __restrict__ fb, const float* __restrict__ feat,
    const float* __restrict__ weight, float* acc)
{
    const int in = v & 0x7FFFF;
    const int k  = (v >> 19) & 31;
    const int ol = (int)(v >> 24);
    float f[16];
    if (BF16) {
        const uint4 pa = fb[(size_t)in * 2];
        const uint4 pb = fb[(size_t)in * 2 + 1];
        f[0]  = __uint_as_float(pa.x << 16); f[1]  = __uint_as_float(pa.x & 0xFFFF0000u);
        f[2]  = __uint_as_float(pa.y << 16); f[3]  = __uint_as_float(pa.y & 0xFFFF0000u);
        f[4]  = __uint_as_float(pa.z << 16); f[5]  = __uint_as_float(pa.z & 0xFFFF0000u);
        f[6]  = __uint_as_float(pa.w << 16); f[7]  = __uint_as_float(pa.w & 0xFFFF0000u);
        f[8]  = __uint_as_float(pb.x << 16); f[9]  = __uint_as_float(pb.x & 0xFFFF0000u);
        f[10] = __uint_as_float(pb.y << 16); f[11] = __uint_as_float(pb.y & 0xFFFF0000u);
        f[12] = __uint_as_float(pb.z << 16); f[13] = __uint_as_float(pb.z & 0xFFFF0000u);
        f[14] = __uint_as_float(pb.w << 16); f[15] = __uint_as_float(pb.w & 0xFFFF0000u);
    } else {
        const float4* f4 = (const float4*)(feat + (size_t)in * CIN);
        const float4 q0 = f4[0], q1 = f4[1], q2 = f4[2], q3 = f4[3];
        f[0]=q0.x; f[1]=q0.y; f[2]=q0.z; f[3]=q0.w;
        f[4]=q1.x; f[5]=q1.y; f[6]=q1.z; f[7]=q1.w;
        f[8]=q2.x; f[9]=q2.y; f[10]=q2.z; f[11]=q2.w;
        f[12]=q3.x; f[13]=q3.y; f[14]=q3.z; f[15]=q3.w;
    }
    const float4* w4 = (const float4*)(weight + k * (CIN * COUT));
    float4 a0 = make_float4(0.f, 0.f, 0.f, 0.f);
    float4 a1 = a0, a2 = a0, a3 = a0;
#define CSTEP(c)                           \
    {                                      \
        const float s_ = f[c];             \
        fma4(a0, s_, w4[(c) * 4 + 0]);     \
        fma4(a1, s_, w4[(c) * 4 + 1]);     \
        fma4(a2, s_, w4[(c) * 4 + 2]);     \
        fma4(a3, s_, w4[(c) * 4 + 3]);     \
    }
    CSTEP(0)  CSTEP(1)  CSTEP(2)  CSTEP(3)
    CSTEP(4)  CSTEP(5)  CSTEP(6)  CSTEP(7)
    CSTEP(8)  CSTEP(9)  CSTEP(10) CSTEP(11)
    CSTEP(12) CSTEP(13) CSTEP(14) CSTEP(15)
#undef CSTEP
    float* ar = acc + ol * ASTRIDE;
    atomicAdd(ar +  0, a0.x); atomicAdd(ar +  1, a0.y);
    atomicAdd(ar +  2, a0.z); atomicAdd(ar +  3, a0.w);
    atomicAdd(ar +  4, a1.x); atomicAdd(ar +  5, a1.y);
    atomicAdd(ar +  6, a1.z); atomicAdd(ar +  7, a1.w);
    atomicAdd(ar +  8, a2.x); atomicAdd(ar +  9, a2.y);
    atomicAdd(ar + 10, a2.z); atomicAdd(ar + 11, a2.w);
    atomicAdd(ar + 12, a3.x); atomicAdd(ar + 13, a3.y);
    atomicAdd(ar + 14, a3.z); atomicAdd(ar + 15, a3.w);
}

// ---------------------------------------------------------------------------
// gemm_full: one block per (bucket, slice) segment; seg == blockIdx.x.
// With round-robin block->XCD dispatch, every block on XCD x reads only
// feature slice x (<=2 MB bf16) -> gathers are L2-resident. Partials in f16,
// nt-stored to keep the slice cached.
// ---------------------------------------------------------------------------
__global__ __launch_bounds__(256) void gemm_full_kernel(
    const uint4* __restrict__ fb,
    const float* __restrict__ weight,
    const int*   __restrict__ cstart,
    const unsigned* __restrict__ entries,
    char*        __restrict__ partials)
{
    __shared__ float acc[256 * ASTRIDE];
    const int seg = blockIdx.x;
    const int b   = seg >> 3;
    const int x   = seg & 7;
    const int tid = threadIdx.x;

    for (int i = tid; i < 256 * ASTRIDE; i += 256) acc[i] = 0.f;
    __syncthreads();

    const int s = cstart[seg];
    const int e = cstart[seg + 1];
    for (int i = s + tid; i < e; i += 256) {
        const unsigned v = __builtin_nontemporal_load(entries + i);
        process_entry<1>(v, fb, (const float*)nullptr, weight, acc);
    }
    __syncthreads();

    // epilogue: thread tid owns local row tid -> f16x16 (32 B) nt-store
    const float* a = acc + tid * ASTRIDE;
    unsigned hw[8];
#pragma unroll
    for (int i = 0; i < 8; ++i) {
        __half2 h = __floats2half2_rn(a[2 * i], a[2 * i + 1]);
        hw[i] = *(unsigned*)&h;
    }
    uvec4 s0 = {hw[0], hw[1], hw[2], hw[3]};
    uvec4 s1 = {hw[4], hw[5], hw[6], hw[7]};
    uvec4* dst = (uvec4*)(partials +
                 ((size_t)x * PROWS + (size_t)b * 256 + tid) * 32);
    __builtin_nontemporal_store(s0, dst);
    __builtin_nontemporal_store(s1, dst + 1);
}

// ---------------------------------------------------------------------------
// reduce: out[row] = bias + sum_x partials[x][row]
// ---------------------------------------------------------------------------
__global__ __launch_bounds__(256) void reduce_kernel(
    const char* __restrict__ partials, const float* __restrict__ bias,
    float* __restrict__ out)
{
    const int row = blockIdx.x * 256 + threadIdx.x;
    if (row >= NSITES) return;
    float s[16];
#pragma unroll
    for (int c = 0; c < 16; ++c) s[c] = bias[c];
#pragma unroll
    for (int x = 0; x < NSLC; ++x) {
        const uvec4* p = (const uvec4*)(partials +
                         ((size_t)x * PROWS + row) * 32);
        const uvec4 u0 = __builtin_nontemporal_load(p);
        const uvec4 u1 = __builtin_nontemporal_load(p + 1);
        const unsigned w[8] = {u0.x, u0.y, u0.z, u0.w, u1.x, u1.y, u1.z, u1.w};
#pragma unroll
        for (int i = 0; i < 8; ++i) {
            __half2 h = *(const __half2*)&w[i];
            const float2 f = __half22float2(h);
            s[2 * i]     += f.x;
            s[2 * i + 1] += f.y;
        }
    }
    float4 o0 = make_float4(s[0], s[1], s[2], s[3]);
    float4 o1 = make_float4(s[4], s[5], s[6], s[7]);
    float4 o2 = make_float4(s[8], s[9], s[10], s[11]);
    float4 o3 = make_float4(s[12], s[13], s[14], s[15]);
    float4* op = (float4*)(out + (size_t)row * COUT);
    op[0] = o0; op[1] = o1; op[2] = o2; op[3] = o3;
}

// ---------------------------------------------------------------------------
// fallback gemm (ws too small for partials): one block per bucket over the
// contiguous range [cstart[8b], cstart[8b+8]); direct out write with bias.
// ---------------------------------------------------------------------------
template <int BF16>
__global__ __launch_bounds__(256) void gemm_fb_kernel(
    const uint4* __restrict__ fb,
    const float* __restrict__ feat,
    const float* __restrict__ weight,
    const float* __restrict__ bias,
    const int*   __restrict__ cstart,
    const unsigned* __restrict__ entries,
    float*       __restrict__ out)
{
    __shared__ float acc[256 * ASTRIDE];
    const int b   = blockIdx.x;
    const int tid = threadIdx.x;
    for (int i = tid; i < 256 * ASTRIDE; i += 256) acc[i] = 0.f;
    __syncthreads();
    const int s = cstart[b * NSLC];
    const int e = cstart[b * NSLC + NSLC];
    for (int i = s + tid; i < e; i += 256)
        process_entry<BF16>(entries[i], fb, feat, weight, acc);
    __syncthreads();
    const int row = b * 256 + tid;
    if (row >= NSITES) return;
    const float* a = acc + tid * ASTRIDE;
    float4 o0, o1, o2, o3;
    o0.x = a[ 0] + bias[ 0]; o0.y = a[ 1] + bias[ 1];
    o0.z = a[ 2] + bias[ 2]; o0.w = a[ 3] + bias[ 3];
    o1.x = a[ 4] + bias[ 4]; o1.y = a[ 5] + bias[ 5];
    o1.z = a[ 6] + bias[ 6]; o1.w = a[ 7] + bias[ 7];
    o2.x = a[ 8] + bias[ 8]; o2.y = a[ 9] + bias[ 9];
    o2.z = a[10] + bias[10]; o2.w = a[11] + bias[11];
    o3.x = a[12] + bias[12]; o3.y = a[13] + bias[13];
    o3.z = a[14] + bias[14]; o3.w = a[15] + bias[15];
    float4* op = (float4*)(out + (size_t)row * COUT);
    op[0] = o0; op[1] = o1; op[2] = o2; op[3] = o3;
}

// ---------------------------------------------------------------------------
extern "C" void kernel_launch(void* const* d_in, const int* in_sizes, int n_in,
                              void* d_out, int out_size, void* d_ws, size_t ws_size,
                              hipStream_t stream)
{
    const float* features  = (const float*)d_in[0];
    const float* weight    = (const float*)d_in[1];
    const float* bias      = (const float*)d_in[2];
    const int*   rules_in  = (const int*)d_in[3];
    const int*   rules_out = (const int*)d_in[4];
    float*       out       = (float*)d_out;

    char* wsb = (char*)d_ws;
    unsigned short* countsT = (unsigned short*)(wsb + OFF_CNT);
    unsigned short* PT      = (unsigned short*)(wsb + OFF_PT);
    int*            Ttot    = (int*)(wsb + OFF_TTOT);
    int*            cstart  = (int*)(wsb + OFF_CST);
    unsigned*       entries = (unsigned*)(wsb + OFF_ENT);
    uint4*          fbf16   = (uint4*)(wsb + OFF_FB);
    char*           partials= wsb + OFF_PART;

    const int tier = (ws_size >= NEED_FULL) ? 2
                   : (ws_size >= NEED_MID)  ? 1 : 0;

    if (tier >= 1) {
        convert_bf16_kernel<<<(NSITES + 255) / 256, 256, 0, stream>>>(
            features, fbf16);
    }

    passA_kernel<<<NBLK, 256, 0, stream>>>(rules_in, rules_out, countsT);
    scanK1_kernel<<<(NSEG + 255) / 256, 256, 0, stream>>>(countsT, PT, Ttot);
    scanK2_kernel<<<1, 1024, 0, stream>>>(Ttot, cstart);
    passB_kernel<<<NBLK, 256, 0, stream>>>(rules_in, rules_out, cstart, PT,
                                           entries);

    if (tier == 2) {
        gemm_full_kernel<<<NSEG, 256, 0, stream>>>(
            fbf16, weight, cstart, entries, partials);
        reduce_kernel<<<(NSITES + 255) / 256, 256, 0, stream>>>(
            partials, bias, out);
    } else if (tier == 1) {
        gemm_fb_kernel<1><<<NBUCK, 256, 0, stream>>>(
            fbf16, features, weight, bias, cstart, entries, out);
    } else {
        gemm_fb_kernel<0><<<NBUCK, 256, 0, stream>>>(
            fbf16, features, weight, bias, cstart, entries, out);
    }
}